// Round 5
// baseline (584.076 us; speedup 1.0000x reference)
//
#include <hip/hip_runtime.h>
#include <hip/hip_bf16.h>
#include <math.h>

#define Bsz 16384
#define HIDc 1024

typedef __attribute__((ext_vector_type(8))) short short8_t;
typedef __attribute__((ext_vector_type(4))) float f32x4;
typedef __attribute__((ext_vector_type(4))) short s16x4;

typedef __attribute__((address_space(1))) const unsigned char* gp1_t;
typedef __attribute__((address_space(3))) unsigned char* lp3_t;

__device__ __forceinline__ float sigf(float x) { return 1.0f / (1.0f + __expf(-x)); }
__device__ __forceinline__ float tanh_fast(float x) {
  x = fminf(fmaxf(x, -10.f), 10.f);
  float t = __expf(2.f * x);
  return (t - 1.f) / (t + 1.f);
}

// Bijective XCD-chunked swizzle (T1, m204 form). r2 evidence: FETCH 573->280 MB.
__device__ __forceinline__ int xcd_map(int bid, int nwg) {
  const int q = nwg >> 3, r = nwg & 7;
  const int xcd = bid & 7, idx = bid >> 3;
  return (xcd < r ? xcd * (q + 1) : r * (q + 1) + (xcd - r) * q) + idx;
}

// Stage one 128x64 bf16 half-tile (16 KB) with 512 threads: 2 x 16B loads each.
// LDS dest linear; k-slot XOR swizzle on the GLOBAL source (rule #21):
// phys slot p of row r holds logical slot p ^ (r&7).
__device__ __forceinline__ void stage_half(const __hip_bfloat16* __restrict__ g, long ld,
                                           __hip_bfloat16* l, int tid) {
#pragma unroll
  for (int it = 0; it < 2; ++it) {
    const int sid = it * 512 + tid;        // 0..1023 16B-slots
    const int row = sid >> 3, slot = sid & 7;
    const int kx = (slot ^ (row & 7)) << 3;
    __builtin_amdgcn_global_load_lds((gp1_t)(g + (long)row * ld + kx),
                                     (lp3_t)(l + sid * 8), 16, 0, 0);
  }
}

// Stage a full 256x64 K-tile (A: rows mBase.., B: rows nBase..) into one buffer.
#define STAGE_TILE(dstbase, t) do {                                              \
    stage_half(Ablk + (long)(t) * 64,             lda, (dstbase),         tid);  \
    stage_half(Ablk + 128 * lda + (long)(t) * 64, lda, (dstbase) + 8192,  tid);  \
    stage_half(Wblk + (long)(t) * 64,             ldw, (dstbase) + 16384, tid);  \
    stage_half(Wblk + 128 * ldw + (long)(t) * 64, ldw, (dstbase) + 24576, tid);  \
  } while (0)

#define READ_A(AhB, qm)                                                          \
  _Pragma("unroll") for (int m_ = 0; m_ < 4; ++m_)                               \
    _Pragma("unroll") for (int k_ = 0; k_ < 2; ++k_)                             \
      a8[m_][k_] = *reinterpret_cast<const short8_t*>(                           \
          (AhB) + ((qm) * 64 + m_ * 16 + lm) * 64 + (((k_ * 4 + hi) ^ l7) << 3));

#define READ_B(BhB, qn)                                                          \
  _Pragma("unroll") for (int n_ = 0; n_ < 2; ++n_)                               \
    _Pragma("unroll") for (int k_ = 0; k_ < 2; ++k_)                             \
      b8[qn][n_][k_] = *reinterpret_cast<const short8_t*>(                       \
          (BhB) + (wcl * 64 + (qn) * 32 + n_ * 16 + lm) * 64 + (((k_ * 4 + hi) ^ l7) << 3));

// One phase: entry barrier, wait own ds_reads, MFMA cluster (T5 setprio),
// optional vmcnt(0) (only at phases 4/8 — nothing younger in flight there),
// closing barrier. Raw s_barrier (NOT __syncthreads) keeps staging loads
// in flight across barriers; sched_barrier(0) per rule #18.
#define PHASE(qm, qn, VM) do {                                                   \
    __builtin_amdgcn_sched_barrier(0);                                           \
    __builtin_amdgcn_s_barrier();                                                \
    asm volatile("s_waitcnt lgkmcnt(0)" ::: "memory");                           \
    __builtin_amdgcn_sched_barrier(0);                                           \
    __builtin_amdgcn_s_setprio(1);                                               \
    _Pragma("unroll") for (int m_ = 0; m_ < 4; ++m_)                             \
      _Pragma("unroll") for (int n_ = 0; n_ < 2; ++n_)                           \
        _Pragma("unroll") for (int k_ = 0; k_ < 2; ++k_)                         \
          acc[qm][qn][m_][n_] = __builtin_amdgcn_mfma_f32_16x16x32_bf16(         \
              a8[m_][k_], b8[qn][n_][k_], acc[qm][qn][m_][n_], 0, 0, 0);         \
    __builtin_amdgcn_s_setprio(0);                                               \
    __builtin_amdgcn_sched_barrier(0);                                           \
    if (VM) {                                                                    \
      asm volatile("s_waitcnt vmcnt(0)" ::: "memory");                           \
      __builtin_amdgcn_sched_barrier(0);                                         \
    }                                                                            \
    __builtin_amdgcn_s_barrier();                                                \
    __builtin_amdgcn_sched_barrier(0);                                           \
  } while (0)

// 256x256 tile, BK=64, 8 waves (2M x 4N), per-wave 128x64 output.
// 8-phase iteration over 2 K-tiles, double-buffered 128 KB LDS.
// EPI 0: G1 — col<1024: rs=sig(v+br)*state; else u=sig(v+bu)
// EPI 1: G2 — col<1024: sem=relu(v+b1)->SN(ld2048); else cx=v+bc->out1
// EPI 2: G3 — nei=relu(v+b2)->out0+1024 (ld2048)
// EPI 3: final_c — cb=tanh(v+auxbf)->out0
// EPI 4: final_g — outf=u*st+(1-u)*cb*sig(v+bg)
template <int EPI>
__global__ __launch_bounds__(512, 2)
void gemm256(const __hip_bfloat16* __restrict__ A, long lda,
             const __hip_bfloat16* __restrict__ Wt, long ldw, int K, int nbx,
             const float* __restrict__ bias0, const float* __restrict__ bias1,
             const __hip_bfloat16* __restrict__ stbf,   // A1 (state at col 1024+)
             const __hip_bfloat16* __restrict__ auxbf,  // EPI3: CXb
             const __hip_bfloat16* __restrict__ CB,     // EPI4
             const __hip_bfloat16* __restrict__ U,      // EPI4
             __hip_bfloat16* __restrict__ out0,
             __hip_bfloat16* __restrict__ out1,
             float* __restrict__ outf) {
  __shared__ __hip_bfloat16 lds[65536];   // 128 KB: 2 bufs x (A 32K + B 32K)
  const int tid = threadIdx.x;
  const int wave = tid >> 6, lane = tid & 63;
  const int wr = wave >> 2, wc = wave & 3, wcl = wc & 1;
  const int lm = lane & 15, hi = lane >> 4, l7 = lane & 7;

  const int wg = xcd_map(blockIdx.x, gridDim.x);
  const long mBase = (long)(wg / nbx) * 256;
  const long nBase = (long)(wg % nbx) * 256;
  const __hip_bfloat16* Ablk = A + mBase * lda;
  const __hip_bfloat16* Wblk = Wt + nBase * ldw;

  f32x4 acc[2][2][4][2];
#pragma unroll
  for (int a = 0; a < 2; ++a)
#pragma unroll
    for (int b = 0; b < 2; ++b)
#pragma unroll
      for (int c = 0; c < 4; ++c)
#pragma unroll
        for (int d = 0; d < 2; ++d) acc[a][b][c][d] = (f32x4){0.f, 0.f, 0.f, 0.f};

  short8_t a8[4][2], b8[2][2][2];

  // Prologue: tile 0 -> buf0, drain, barrier.
  STAGE_TILE(lds, 0);
  asm volatile("s_waitcnt vmcnt(0)" ::: "memory");
  __builtin_amdgcn_s_barrier();
  __builtin_amdgcn_sched_barrier(0);

  const int NI = K >> 7;           // 2 K-tiles per iteration
  for (int i = 0; i < NI; ++i) {
    {  // K-tile E=2i in buf0; stage tile O=2i+1 -> buf1 in phase 1
      const __hip_bfloat16* AhB = lds + wr * 8192;
      const __hip_bfloat16* BhB = lds + 16384 + (wc >> 1) * 8192;
      READ_A(AhB, 0); READ_B(BhB, 0);
      STAGE_TILE(lds + 32768, 2 * i + 1);
      PHASE(0, 0, 0);
      READ_B(BhB, 1);
      PHASE(0, 1, 0);
      READ_A(AhB, 1);
      PHASE(1, 0, 0);
      PHASE(1, 1, 1);              // vmcnt(0): tile O landed
    }
    {  // K-tile O=2i+1 in buf1; stage tile 2i+2 -> buf0 in phase 5
      const __hip_bfloat16* AhB = lds + 32768 + wr * 8192;
      const __hip_bfloat16* BhB = lds + 32768 + 16384 + (wc >> 1) * 8192;
      READ_A(AhB, 0); READ_B(BhB, 0);
      if (i + 1 < NI) STAGE_TILE(lds, 2 * i + 2);
      PHASE(0, 0, 0);
      READ_B(BhB, 1);
      PHASE(0, 1, 0);
      READ_A(AhB, 1);
      PHASE(1, 0, 0);
      PHASE(1, 1, 1);              // vmcnt(0): next even tile landed (or no-op)
    }
  }

  // Epilogue: wave writes 128x64 at (mBase + wr*128, nBase + wc*64).
#pragma unroll
  for (int qm = 0; qm < 2; ++qm)
#pragma unroll
    for (int qn = 0; qn < 2; ++qn)
#pragma unroll
      for (int m = 0; m < 4; ++m)
#pragma unroll
        for (int n = 0; n < 2; ++n)
#pragma unroll
          for (int j = 0; j < 4; ++j) {
            const long row = mBase + wr * 128 + qm * 64 + m * 16 + hi * 4 + j;
            const int col = (int)nBase + wc * 64 + qn * 32 + n * 16 + lm;
            const float v = acc[qm][qn][m][n][j];
            if (EPI == 0) {
              if (col < HIDc) {
                float rr = sigf(v + bias0[col]);
                float st = __bfloat162float(stbf[row * 2048 + 1024 + col]);
                out0[row * HIDc + col] = __float2bfloat16(rr * st);
              } else {
                int c = col - HIDc;
                out1[row * HIDc + c] = __float2bfloat16(sigf(v + bias1[c]));
              }
            } else if (EPI == 1) {
              if (col < HIDc) {
                out0[row * 2048 + col] = __float2bfloat16(fmaxf(v + bias0[col], 0.f));
              } else {
                int c = col - HIDc;
                out1[row * HIDc + c] = __float2bfloat16(v + bias1[c]);
              }
            } else if (EPI == 2) {
              out0[row * 2048 + HIDc + col] = __float2bfloat16(fmaxf(v + bias0[col], 0.f));
            } else if (EPI == 3) {
              const long idx = row * HIDc + col;
              out0[idx] = __float2bfloat16(tanh_fast(v + __bfloat162float(auxbf[idx])));
            } else {
              const long idx = row * HIDc + col;
              float g = sigf(v + bias0[col]);
              float u = __bfloat162float(U[idx]);
              float cb = __bfloat162float(CB[idx]);
              float st = __bfloat162float(stbf[row * 2048 + 1024 + col]);
              outf[idx] = u * st + (1.f - u) * cb * g;
            }
          }
}

// Pack activations to bf16: A1 = [x | state] (B x 2048), NB = neighbors (B x 1024)
__global__ void convert_k(const float4* __restrict__ in4, const float4* __restrict__ st4,
                          __hip_bfloat16* __restrict__ A1, __hip_bfloat16* __restrict__ NB) {
  const long NI4 = (long)Bsz * 2048 / 4;
  const long NS4 = (long)Bsz * 1024 / 4;
  for (long i = (long)blockIdx.x * blockDim.x + threadIdx.x; i < NI4 + NS4;
       i += (long)gridDim.x * blockDim.x) {
    float4 v;
    __hip_bfloat16* dst;
    if (i < NI4) {
      v = in4[i];
      long e = i << 2;
      long row = e >> 11;
      int col = (int)(e & 2047);
      dst = (col < 1024) ? (A1 + row * 2048 + col) : (NB + row * 1024 + (col - 1024));
    } else {
      long j = i - NI4;
      v = st4[j];
      long e = j << 2;
      long row = e >> 10;
      int col = (int)(e & 1023);
      dst = A1 + row * 2048 + 1024 + col;
    }
    union { __hip_bfloat16 h[4]; s16x4 s; } u;
    u.h[0] = __float2bfloat16(v.x);
    u.h[1] = __float2bfloat16(v.y);
    u.h[2] = __float2bfloat16(v.z);
    u.h[3] = __float2bfloat16(v.w);
    *reinterpret_cast<s16x4*>(dst) = u.s;
  }
}

// out[n*ldout + k] = bf16(in[k*ldin + n]); grid = (K/32, N/32), block = (32,8)
__global__ void transpose_k(const float* __restrict__ in, int ldin,
                            __hip_bfloat16* __restrict__ out, long ldout) {
  __shared__ float t[32][33];
  const int k0 = blockIdx.x * 32, n0 = blockIdx.y * 32;
  const int tx = threadIdx.x, ty = threadIdx.y;
#pragma unroll
  for (int dy = 0; dy < 32; dy += 8)
    t[ty + dy][tx] = in[(long)(k0 + ty + dy) * ldin + n0 + tx];
  __syncthreads();
#pragma unroll
  for (int dy = 0; dy < 32; dy += 8)
    out[(long)(n0 + ty + dy) * ldout + k0 + tx] = __float2bfloat16(t[tx][ty + dy]);
}

extern "C" void kernel_launch(void* const* d_in, const int* in_sizes, int n_in,
                              void* d_out, int out_size, void* d_ws, size_t ws_size,
                              hipStream_t stream) {
  const float* inputs = (const float*)d_in[0];
  const float* state = (const float*)d_in[1];
  const float* Wr = (const float*)d_in[2];
  const float* br = (const float*)d_in[3];
  const float* Wu = (const float*)d_in[4];
  const float* bu = (const float*)d_in[5];
  const float* Wc = (const float*)d_in[6];
  const float* bc = (const float*)d_in[7];
  const float* W1 = (const float*)d_in[8];
  const float* b1 = (const float*)d_in[9];
  const float* W2 = (const float*)d_in[10];
  const float* b2 = (const float*)d_in[11];
  const float* Wg = (const float*)d_in[12];
  const float* bg = (const float*)d_in[13];
  float* out = (float*)d_out;

  char* ws = (char*)d_ws;
  __hip_bfloat16* A1    = (__hip_bfloat16*)(ws);                 // 64 MB [x|state]
  __hip_bfloat16* NB    = (__hip_bfloat16*)(ws + 67108864L);     // 32 MB neighbors -> CB
  __hip_bfloat16* RS    = (__hip_bfloat16*)(ws + 100663296L);    // 32 MB r*state
  __hip_bfloat16* Ub    = (__hip_bfloat16*)(ws + 134217728L);    // 32 MB u
  __hip_bfloat16* SN    = (__hip_bfloat16*)(ws + 167772160L);    // 64 MB [sem|nei]
  __hip_bfloat16* CXb   = (__hip_bfloat16*)(ws + 234881024L);    // 32 MB x@Wc_top+bc
  __hip_bfloat16* Wru_t = (__hip_bfloat16*)(ws + 268435456L);    // 8 MB  (2048 x 2048)
  __hip_bfloat16* W1cx_t= (__hip_bfloat16*)(ws + 276824064L);    // 4 MB  (2048 x 1024)
  __hip_bfloat16* Wcb_t = (__hip_bfloat16*)(ws + 281018368L);    // 2 MB  (1024 x 1024)
  __hip_bfloat16* W2_t  = (__hip_bfloat16*)(ws + 283115520L);    // 2 MB  (1024 x 1024)
  __hip_bfloat16* Wg_t  = (__hip_bfloat16*)(ws + 285212672L);    // 4 MB  (1024 x 2048)
  __hip_bfloat16* CB    = NB;   // NB dead after G3; reuse for tanh(c)

  convert_k<<<2048, 256, 0, stream>>>((const float4*)inputs, (const float4*)state, A1, NB);

  dim3 tb(32, 8);
  transpose_k<<<dim3(64, 32), tb, 0, stream>>>(Wr, 1024, Wru_t, 2048);
  transpose_k<<<dim3(64, 32), tb, 0, stream>>>(Wu, 1024, Wru_t + (long)1024 * 2048, 2048);
  transpose_k<<<dim3(32, 32), tb, 0, stream>>>(W1, 1024, W1cx_t, 1024);
  transpose_k<<<dim3(32, 32), tb, 0, stream>>>(Wc, 1024, W1cx_t + (long)1024 * 1024, 1024);
  transpose_k<<<dim3(32, 32), tb, 0, stream>>>(Wc + (long)1024 * 1024, 1024, Wcb_t, 1024);
  transpose_k<<<dim3(32, 32), tb, 0, stream>>>(W2, 1024, W2_t, 1024);
  transpose_k<<<dim3(64, 32), tb, 0, stream>>>(Wg, 1024, Wg_t, 2048);

  // G1: [x|state] @ [Wr|Wu] -> rs, u   (64 m x 8 n = 512 blocks)
  gemm256<0><<<512, 512, 0, stream>>>(A1, 2048, Wru_t, 2048, 2048, 8,
                                      br, bu, A1, nullptr, nullptr, nullptr,
                                      RS, Ub, nullptr);
  // G2: x @ [W1|Wc_top] -> sem, cx
  gemm256<1><<<512, 512, 0, stream>>>(A1, 2048, W1cx_t, 1024, 1024, 8,
                                      b1, bc, nullptr, nullptr, nullptr, nullptr,
                                      SN, CXb, nullptr);
  // G3: neighbors @ W2 -> nei
  gemm256<2><<<256, 512, 0, stream>>>(NB, 1024, W2_t, 1024, 1024, 4,
                                      b2, nullptr, nullptr, nullptr, nullptr, nullptr,
                                      SN, nullptr, nullptr);
  // final_c: cb = tanh(cx + rs @ Wc_bot^T) -> CB
  gemm256<3><<<256, 512, 0, stream>>>(RS, 1024, Wcb_t, 1024, 1024, 4,
                                      nullptr, nullptr, nullptr, CXb, nullptr, nullptr,
                                      CB, nullptr, nullptr);
  // final_g: out = u*state + (1-u)*cb*sigmoid([sem|nei] @ Wg^T + bg)
  gemm256<4><<<256, 512, 0, stream>>>(SN, 2048, Wg_t, 2048, 2048, 4,
                                      bg, nullptr, A1, nullptr, CB, Ub,
                                      nullptr, nullptr, out);
}

// Round 6
// 570.540 us; speedup vs baseline: 1.0237x; 1.0237x over previous
//
#include <hip/hip_runtime.h>
#include <hip/hip_bf16.h>
#include <math.h>

#define Bsz 16384
#define HIDc 1024

typedef __attribute__((ext_vector_type(8))) short short8_t;
typedef __attribute__((ext_vector_type(4))) float f32x4;
typedef __attribute__((ext_vector_type(4))) short s16x4;

typedef __attribute__((address_space(1))) const unsigned char* gp1_t;
typedef __attribute__((address_space(3))) unsigned char* lp3_t;

__device__ __forceinline__ float sigf(float x) { return 1.0f / (1.0f + __expf(-x)); }
__device__ __forceinline__ float tanh_fast(float x) {
  x = fminf(fmaxf(x, -10.f), 10.f);
  float t = __expf(2.f * x);
  return (t - 1.f) / (t + 1.f);
}

// Bijective XCD-chunked swizzle (T1). r2 evidence: FETCH 573->280 MB.
__device__ __forceinline__ int xcd_map(int bid, int nwg) {
  const int q = nwg >> 3, r = nwg & 7;
  const int xcd = bid & 7, idx = bid >> 3;
  return (xcd < r ? xcd * (q + 1) : r * (q + 1) + (xcd - r) * q) + idx;
}

// inline-asm ds_read_b128 (compiler alias analysis would otherwise insert
// conservative waits against in-flight global_load_lds into the same array)
#define DSR(dst, addr, IMM) \
  asm volatile("ds_read_b128 %0, %1 offset:" IMM : "=v"(dst) : "v"(addr))

// Stage all 6 16B-loads of one 256x64 A + 128x64 B K-step into buffer BIDX.
// LDS dest linear (wave-uniform + lane*16); XOR slot swizzle pre-applied on the
// GLOBAL source col (rule #21), identical to the r4-proven conflict-free layout.
#define STAGE_ADV(BIDX) do {                                                                   \
    __hip_bfloat16* db_ = lds + (BIDX) * 24576;                                                \
    __builtin_amdgcn_global_load_lds((gp1_t)pa0, (lp3_t)(db_ + tid * 8), 16, 0, 0);            \
    __builtin_amdgcn_global_load_lds((gp1_t)pa1, (lp3_t)(db_ + (512 + tid) * 8), 16, 0, 0);    \
    __builtin_amdgcn_global_load_lds((gp1_t)pa2, (lp3_t)(db_ + (1024 + tid) * 8), 16, 0, 0);   \
    __builtin_amdgcn_global_load_lds((gp1_t)pa3, (lp3_t)(db_ + (1536 + tid) * 8), 16, 0, 0);   \
    __builtin_amdgcn_global_load_lds((gp1_t)pb0, (lp3_t)(db_ + 16384 + tid * 8), 16, 0, 0);    \
    __builtin_amdgcn_global_load_lds((gp1_t)pb1, (lp3_t)(db_ + 16384 + (512 + tid) * 8), 16, 0, 0); \
    pa0 += 64; pa1 += 64; pa2 += 64; pa3 += 64; pb0 += 64; pb1 += 64;                          \
  } while (0)

// 256x128 tile, BK=64, 8 waves (4M x 2N), per-wave 64x64 out. Triple-buffered
// 144 KB LDS; stage s+2 during s; entry vmcnt(6) (counted, never drains the
// pipeline); raw s_barrier (one per K-step, no compiler drain).
// EPI 0: G1 — col<1024: rs=sig(v+br)*state; else u=sig(v+bu)
// EPI 1: G2 — col<1024: sem=relu(v+b1)->SN(ld2048); else cx=v+bc->out1
// EPI 2: G3 — nei=relu(v+b2)->out0+1024 (ld2048)
// EPI 3: final_c — cb=tanh(v+auxbf)->out0
// EPI 4: final_g — outf=u*st+(1-u)*cb*sig(v+bg)
template <int EPI>
__global__ __launch_bounds__(512, 2)
void gemm256(const __hip_bfloat16* __restrict__ A, long lda,
             const __hip_bfloat16* __restrict__ Wt, long ldw, int nbx,
             const float* __restrict__ bias0, const float* __restrict__ bias1,
             const __hip_bfloat16* __restrict__ stbf,   // A1 (state at col 1024+)
             const __hip_bfloat16* __restrict__ auxbf,  // EPI3: CXb
             const __hip_bfloat16* __restrict__ CB,     // EPI4
             const __hip_bfloat16* __restrict__ U,      // EPI4
             __hip_bfloat16* __restrict__ out0,
             __hip_bfloat16* __restrict__ out1,
             float* __restrict__ outf) {
  constexpr int KC = (EPI == 0 || EPI == 4) ? 2048 : 1024;
  constexpr int NS = KC / 64;
  __shared__ __hip_bfloat16 lds[3 * 24576];   // 3 bufs x (A 32KB + B 16KB)

  const int tid = threadIdx.x;
  const int wave = tid >> 6, lane = tid & 63;
  const int wr = wave >> 1, wc = wave & 1;
  const int lm = lane & 15, hi = lane >> 4, l7 = lane & 7;

  const int wg = xcd_map(blockIdx.x, gridDim.x);
  const long mBase = (long)(wg / nbx) * 256;
  const long nBase = (long)(wg % nbx) * 128;
  const __hip_bfloat16* Ablk = A + mBase * lda;
  const __hip_bfloat16* Wblk = Wt + nBase * ldw;

  // Pre-swizzled global staging pointers (advance 64 cols per staged step).
  const int sidA[4] = {tid, 512 + tid, 1024 + tid, 1536 + tid};
  const __hip_bfloat16 *pa0, *pa1, *pa2, *pa3, *pb0, *pb1;
  {
    int r0 = sidA[0] >> 3, r1 = sidA[1] >> 3, r2 = sidA[2] >> 3, r3 = sidA[3] >> 3;
    pa0 = Ablk + (long)r0 * lda + (((sidA[0] & 7) ^ (r0 & 7)) << 3);
    pa1 = Ablk + (long)r1 * lda + (((sidA[1] & 7) ^ (r1 & 7)) << 3);
    pa2 = Ablk + (long)r2 * lda + (((sidA[2] & 7) ^ (r2 & 7)) << 3);
    pa3 = Ablk + (long)r3 * lda + (((sidA[3] & 7) ^ (r3 & 7)) << 3);
    pb0 = Wblk + (long)r0 * ldw + (((sidA[0] & 7) ^ (r0 & 7)) << 3);
    pb1 = Wblk + (long)r1 * ldw + (((sidA[1] & 7) ^ (r1 & 7)) << 3);
  }

  const unsigned ldsbase = (unsigned)(size_t)(void*)lds;
  const unsigned laneA = (unsigned)((wr * 64 + lm) * 128 + ((hi ^ l7) << 4));
  const unsigned laneB = (unsigned)((wc * 64 + lm) * 128 + ((hi ^ l7) << 4));

  f32x4 acc[4][4];
#pragma unroll
  for (int m = 0; m < 4; ++m)
#pragma unroll
    for (int n = 0; n < 4; ++n) acc[m][n] = (f32x4){0.f, 0.f, 0.f, 0.f};

  STAGE_ADV(0);        // K-step 0 -> buf0
  STAGE_ADV(1);        // K-step 1 -> buf1

  for (int s = 0; s < NS; ++s) {
    // Counted entry wait: allow the next step's 6 loads to stay in flight;
    // in-order vmcnt retirement guarantees buf[s%3] has fully landed.
    if (s == NS - 1) asm volatile("s_waitcnt vmcnt(0)" ::: "memory");
    else             asm volatile("s_waitcnt vmcnt(6)" ::: "memory");
    __builtin_amdgcn_s_barrier();

    const unsigned base = ldsbase + (unsigned)((s % 3) * 49152);
    unsigned a0 = base + laneA;
    unsigned b0 = base + 32768u + laneB;
    unsigned a1 = a0 ^ 64u, b1 = b0 ^ 64u;   // k-half toggle = slot-bit2 = byte 64
    short8_t a8[4][2], b8[4][2];
    DSR(a8[0][0], a0, "0"); DSR(a8[1][0], a0, "2048"); DSR(a8[2][0], a0, "4096"); DSR(a8[3][0], a0, "6144");
    DSR(a8[0][1], a1, "0"); DSR(a8[1][1], a1, "2048"); DSR(a8[2][1], a1, "4096"); DSR(a8[3][1], a1, "6144");
    DSR(b8[0][0], b0, "0"); DSR(b8[1][0], b0, "2048"); DSR(b8[2][0], b0, "4096"); DSR(b8[3][0], b0, "6144");
    DSR(b8[0][1], b1, "0"); DSR(b8[1][1], b1, "2048"); DSR(b8[2][1], b1, "4096"); DSR(b8[3][1], b1, "6144");

    if (s + 2 < NS) STAGE_ADV((s + 2) % 3);   // restage the buffer freed at s-1

    asm volatile("s_waitcnt lgkmcnt(0)" ::: "memory");
    __builtin_amdgcn_sched_barrier(0);        // rule #18: pin MFMA below the wait
    __builtin_amdgcn_s_setprio(1);
#pragma unroll
    for (int ks = 0; ks < 2; ++ks)
#pragma unroll
      for (int mf = 0; mf < 4; ++mf)
#pragma unroll
        for (int nf = 0; nf < 4; ++nf)
          acc[mf][nf] = __builtin_amdgcn_mfma_f32_16x16x32_bf16(a8[mf][ks], b8[nf][ks],
                                                                acc[mf][nf], 0, 0, 0);
    __builtin_amdgcn_s_setprio(0);
  }

  // Epilogue: wave writes 64x64 at (mBase + wr*64, nBase + wc*64).
#pragma unroll
  for (int mf = 0; mf < 4; ++mf)
#pragma unroll
    for (int nf = 0; nf < 4; ++nf)
#pragma unroll
      for (int j = 0; j < 4; ++j) {
        const long row = mBase + wr * 64 + mf * 16 + hi * 4 + j;
        const int col = (int)nBase + wc * 64 + nf * 16 + lm;
        const float v = acc[mf][nf][j];
        if (EPI == 0) {
          if (col < HIDc) {
            float rr = sigf(v + bias0[col]);
            float st = __bfloat162float(stbf[row * 2048 + 1024 + col]);
            out0[row * HIDc + col] = __float2bfloat16(rr * st);
          } else {
            int c = col - HIDc;
            out1[row * HIDc + c] = __float2bfloat16(sigf(v + bias1[c]));
          }
        } else if (EPI == 1) {
          if (col < HIDc) {
            out0[row * 2048 + col] = __float2bfloat16(fmaxf(v + bias0[col], 0.f));
          } else {
            int c = col - HIDc;
            out1[row * HIDc + c] = __float2bfloat16(v + bias1[c]);
          }
        } else if (EPI == 2) {
          out0[row * 2048 + HIDc + col] = __float2bfloat16(fmaxf(v + bias0[col], 0.f));
        } else if (EPI == 3) {
          const long idx = row * HIDc + col;
          out0[idx] = __float2bfloat16(tanh_fast(v + __bfloat162float(auxbf[idx])));
        } else {
          const long idx = row * HIDc + col;
          float g = sigf(v + bias0[col]);
          float u = __bfloat162float(U[idx]);
          float cb = __bfloat162float(CB[idx]);
          float st = __bfloat162float(stbf[row * 2048 + 1024 + col]);
          outf[idx] = u * st + (1.f - u) * cb * g;
        }
      }
}

// Pack activations to bf16: A1 = [x | state] (B x 2048), NB = neighbors (B x 1024)
__global__ void convert_k(const float4* __restrict__ in4, const float4* __restrict__ st4,
                          __hip_bfloat16* __restrict__ A1, __hip_bfloat16* __restrict__ NB) {
  const long NI4 = (long)Bsz * 2048 / 4;
  const long NS4 = (long)Bsz * 1024 / 4;
  for (long i = (long)blockIdx.x * blockDim.x + threadIdx.x; i < NI4 + NS4;
       i += (long)gridDim.x * blockDim.x) {
    float4 v;
    __hip_bfloat16* dst;
    if (i < NI4) {
      v = in4[i];
      long e = i << 2;
      long row = e >> 11;
      int col = (int)(e & 2047);
      dst = (col < 1024) ? (A1 + row * 2048 + col) : (NB + row * 1024 + (col - 1024));
    } else {
      long j = i - NI4;
      v = st4[j];
      long e = j << 2;
      long row = e >> 10;
      int col = (int)(e & 1023);
      dst = A1 + row * 2048 + 1024 + col;
    }
    union { __hip_bfloat16 h[4]; s16x4 s; } u;
    u.h[0] = __float2bfloat16(v.x);
    u.h[1] = __float2bfloat16(v.y);
    u.h[2] = __float2bfloat16(v.z);
    u.h[3] = __float2bfloat16(v.w);
    *reinterpret_cast<s16x4*>(dst) = u.s;
  }
}

// out[n*ldout + k] = bf16(in[k*ldin + n]); grid = (K/32, N/32), block = (32,8)
__global__ void transpose_k(const float* __restrict__ in, int ldin,
                            __hip_bfloat16* __restrict__ out, long ldout) {
  __shared__ float t[32][33];
  const int k0 = blockIdx.x * 32, n0 = blockIdx.y * 32;
  const int tx = threadIdx.x, ty = threadIdx.y;
#pragma unroll
  for (int dy = 0; dy < 32; dy += 8)
    t[ty + dy][tx] = in[(long)(k0 + ty + dy) * ldin + n0 + tx];
  __syncthreads();
#pragma unroll
  for (int dy = 0; dy < 32; dy += 8)
    out[(long)(n0 + ty + dy) * ldout + k0 + tx] = __float2bfloat16(t[tx][ty + dy]);
}

extern "C" void kernel_launch(void* const* d_in, const int* in_sizes, int n_in,
                              void* d_out, int out_size, void* d_ws, size_t ws_size,
                              hipStream_t stream) {
  const float* inputs = (const float*)d_in[0];
  const float* state = (const float*)d_in[1];
  const float* Wr = (const float*)d_in[2];
  const float* br = (const float*)d_in[3];
  const float* Wu = (const float*)d_in[4];
  const float* bu = (const float*)d_in[5];
  const float* Wc = (const float*)d_in[6];
  const float* bc = (const float*)d_in[7];
  const float* W1 = (const float*)d_in[8];
  const float* b1 = (const float*)d_in[9];
  const float* W2 = (const float*)d_in[10];
  const float* b2 = (const float*)d_in[11];
  const float* Wg = (const float*)d_in[12];
  const float* bg = (const float*)d_in[13];
  float* out = (float*)d_out;

  char* ws = (char*)d_ws;
  __hip_bfloat16* A1    = (__hip_bfloat16*)(ws);                 // 64 MB [x|state]
  __hip_bfloat16* NB    = (__hip_bfloat16*)(ws + 67108864L);     // 32 MB neighbors -> CB
  __hip_bfloat16* RS    = (__hip_bfloat16*)(ws + 100663296L);    // 32 MB r*state
  __hip_bfloat16* Ub    = (__hip_bfloat16*)(ws + 134217728L);    // 32 MB u
  __hip_bfloat16* SN    = (__hip_bfloat16*)(ws + 167772160L);    // 64 MB [sem|nei]
  __hip_bfloat16* CXb   = (__hip_bfloat16*)(ws + 234881024L);    // 32 MB x@Wc_top+bc
  __hip_bfloat16* Wru_t = (__hip_bfloat16*)(ws + 268435456L);    // 8 MB  (2048 x 2048)
  __hip_bfloat16* W1cx_t= (__hip_bfloat16*)(ws + 276824064L);    // 4 MB  (2048 x 1024)
  __hip_bfloat16* Wcb_t = (__hip_bfloat16*)(ws + 281018368L);    // 2 MB  (1024 x 1024)
  __hip_bfloat16* W2_t  = (__hip_bfloat16*)(ws + 283115520L);    // 2 MB  (1024 x 1024)
  __hip_bfloat16* Wg_t  = (__hip_bfloat16*)(ws + 285212672L);    // 4 MB  (1024 x 2048)
  __hip_bfloat16* CB    = NB;   // NB dead after G3; reuse for tanh(c)

  convert_k<<<2048, 256, 0, stream>>>((const float4*)inputs, (const float4*)state, A1, NB);

  dim3 tb(32, 8);
  transpose_k<<<dim3(64, 32), tb, 0, stream>>>(Wr, 1024, Wru_t, 2048);
  transpose_k<<<dim3(64, 32), tb, 0, stream>>>(Wu, 1024, Wru_t + (long)1024 * 2048, 2048);
  transpose_k<<<dim3(32, 32), tb, 0, stream>>>(W1, 1024, W1cx_t, 1024);
  transpose_k<<<dim3(32, 32), tb, 0, stream>>>(Wc, 1024, W1cx_t + (long)1024 * 1024, 1024);
  transpose_k<<<dim3(32, 32), tb, 0, stream>>>(Wc + (long)1024 * 1024, 1024, Wcb_t, 1024);
  transpose_k<<<dim3(32, 32), tb, 0, stream>>>(W2, 1024, W2_t, 1024);
  transpose_k<<<dim3(64, 32), tb, 0, stream>>>(Wg, 1024, Wg_t, 2048);

  // G1: [x|state] @ [Wr|Wu] -> rs, u   (64 m x 16 n)
  gemm256<0><<<1024, 512, 0, stream>>>(A1, 2048, Wru_t, 2048, 16,
                                       br, bu, A1, nullptr, nullptr, nullptr,
                                       RS, Ub, nullptr);
  // G2: x @ [W1|Wc_top] -> sem, cx
  gemm256<1><<<1024, 512, 0, stream>>>(A1, 2048, W1cx_t, 1024, 16,
                                       b1, bc, nullptr, nullptr, nullptr, nullptr,
                                       SN, CXb, nullptr);
  // G3: neighbors @ W2 -> nei
  gemm256<2><<<512, 512, 0, stream>>>(NB, 1024, W2_t, 1024, 8,
                                      b2, nullptr, nullptr, nullptr, nullptr, nullptr,
                                      SN, nullptr, nullptr);
  // final_c: cb = tanh(cx + rs @ Wc_bot^T) -> CB
  gemm256<3><<<512, 512, 0, stream>>>(RS, 1024, Wcb_t, 1024, 8,
                                      nullptr, nullptr, nullptr, CXb, nullptr, nullptr,
                                      CB, nullptr, nullptr);
  // final_g: out = u*state + (1-u)*cb*sigmoid([sem|nei] @ Wg^T + bg)
  gemm256<4><<<512, 512, 0, stream>>>(SN, 2048, Wg_t, 2048, 8,
                                      bg, nullptr, A1, nullptr, CB, Ub,
                                      nullptr, nullptr, out);
}

// Round 7
// 522.366 us; speedup vs baseline: 1.1181x; 1.0922x over previous
//
#include <hip/hip_runtime.h>
#include <hip/hip_bf16.h>
#include <math.h>

#define Bsz 16384
#define HIDc 1024

typedef __attribute__((ext_vector_type(8))) short short8_t;
typedef __attribute__((ext_vector_type(4))) float f32x4;
typedef __attribute__((ext_vector_type(4))) short s16x4;

typedef __attribute__((address_space(1))) const unsigned char* gp1_t;
typedef __attribute__((address_space(3))) unsigned char* lp3_t;

__device__ __forceinline__ float sigf(float x) { return 1.0f / (1.0f + __expf(-x)); }
__device__ __forceinline__ float tanh_fast(float x) {
  x = fminf(fmaxf(x, -10.f), 10.f);
  float t = __expf(2.f * x);
  return (t - 1.f) / (t + 1.f);
}

// Bijective XCD-chunked swizzle (T1). r2 evidence: FETCH 573->280 MB.
__device__ __forceinline__ int xcd_map(int bid, int nwg) {
  const int q = nwg >> 3, r = nwg & 7;
  const int xcd = bid & 7, idx = bid >> 3;
  return (xcd < r ? xcd * (q + 1) : r * (q + 1) + (xcd - r) * q) + idx;
}

// inline-asm ds_read_b128: keeps compiler alias analysis from inserting
// conservative waits against in-flight global_load_lds (r5's failure).
#define DSR(dst, addr, IMM) \
  asm volatile("ds_read_b128 %0, %1 offset:" IMM : "=v"(dst) : "v"(addr))

// Stage one 256x64 A half + 256x64 B half (64 KB) into buffer at elem offset
// BUFB. 8 x 16B loads/thread. LDS dest linear (wave-uniform + lane*16); XOR
// slot swizzle pre-applied on the GLOBAL source col (rule #21) — the
// r4/r6-proven conflict-free layout.
#define STAGE_ADV(BUFB) do {                                                                     \
    __hip_bfloat16* db_ = lds + (BUFB);                                                          \
    __builtin_amdgcn_global_load_lds((gp1_t)pa0, (lp3_t)(db_ + tid * 8), 16, 0, 0);              \
    __builtin_amdgcn_global_load_lds((gp1_t)pa1, (lp3_t)(db_ + (512 + tid) * 8), 16, 0, 0);      \
    __builtin_amdgcn_global_load_lds((gp1_t)pa2, (lp3_t)(db_ + (1024 + tid) * 8), 16, 0, 0);     \
    __builtin_amdgcn_global_load_lds((gp1_t)pa3, (lp3_t)(db_ + (1536 + tid) * 8), 16, 0, 0);     \
    __builtin_amdgcn_global_load_lds((gp1_t)pb0, (lp3_t)(db_ + 16384 + tid * 8), 16, 0, 0);      \
    __builtin_amdgcn_global_load_lds((gp1_t)pb1, (lp3_t)(db_ + 16384 + (512 + tid) * 8), 16, 0, 0); \
    __builtin_amdgcn_global_load_lds((gp1_t)pb2, (lp3_t)(db_ + 16384 + (1024 + tid) * 8), 16, 0, 0); \
    __builtin_amdgcn_global_load_lds((gp1_t)pb3, (lp3_t)(db_ + 16384 + (1536 + tid) * 8), 16, 0, 0); \
    pa0 += 64; pa1 += 64; pa2 += 64; pa3 += 64;                                                  \
    pb0 += 64; pb1 += 64; pb2 += 64; pb3 += 64;                                                  \
  } while (0)

// 256x256 tile, BK=64, 8 waves (2M x 4N), per-wave 128x64 out. Two 64 KB LDS
// buffers (1 block/CU), stage-ahead-2, counted entry vmcnt(8); two sub-phases
// per K-tile (ks=0/1: 12 asm ds_read_b128 + 32 MFMA each); 2 raw s_barriers
// per K-tile; restage after barrier #2 (all waves' reads retired => no race).
// EPI 0: G1 — col<1024: rs=sig(v+br)*state; else u=sig(v+bu)
// EPI 1: G2 — col<1024: sem=relu(v+b1)->SN(ld2048); else cx=v+bc->out1
// EPI 2: G3 — nei=relu(v+b2)->out0+1024 (ld2048)
// EPI 3: final_c — cb=tanh(v+auxbf)->out0
// EPI 4: final_g — outf=u*st+(1-u)*cb*sig(v+bg)
template <int EPI>
__global__ __launch_bounds__(512, 2)
void gemm256(const __hip_bfloat16* __restrict__ A, long lda,
             const __hip_bfloat16* __restrict__ Wt, long ldw, int nbx,
             const float* __restrict__ bias0, const float* __restrict__ bias1,
             const __hip_bfloat16* __restrict__ stbf,   // A1 (state at col 1024+)
             const __hip_bfloat16* __restrict__ auxbf,  // EPI3: CXb
             const __hip_bfloat16* __restrict__ CB,     // EPI4
             const __hip_bfloat16* __restrict__ U,      // EPI4
             __hip_bfloat16* __restrict__ out0,
             __hip_bfloat16* __restrict__ out1,
             float* __restrict__ outf) {
  constexpr int KC = (EPI == 0 || EPI == 4) ? 2048 : 1024;
  constexpr int NS = KC / 64;
  __shared__ __hip_bfloat16 lds[2 * 32768];   // 128 KB: 2 x (A 32KB + B 32KB)

  const int tid = threadIdx.x;
  const int wave = tid >> 6, lane = tid & 63;
  const int wr = wave >> 2, wc = wave & 3;
  const int lm = lane & 15, hi = lane >> 4, l7 = lane & 7;

  const int wg = xcd_map(blockIdx.x, gridDim.x);
  const long mBase = (long)(wg / nbx) * 256;
  const long nBase = (long)(wg % nbx) * 256;
  const __hip_bfloat16* Ablk = A + mBase * lda;
  const __hip_bfloat16* Wblk = Wt + nBase * ldw;

  // Pre-swizzled global staging pointers (advance 64 cols per staged K-tile).
  const __hip_bfloat16 *pa0, *pa1, *pa2, *pa3, *pb0, *pb1, *pb2, *pb3;
  {
    const int s0 = tid, s1 = 512 + tid, s2 = 1024 + tid, s3 = 1536 + tid;
    const int r0 = s0 >> 3, r1 = s1 >> 3, r2 = s2 >> 3, r3 = s3 >> 3;
    const int c0 = ((s0 & 7) ^ (r0 & 7)) << 3, c1 = ((s1 & 7) ^ (r1 & 7)) << 3;
    const int c2 = ((s2 & 7) ^ (r2 & 7)) << 3, c3 = ((s3 & 7) ^ (r3 & 7)) << 3;
    pa0 = Ablk + (long)r0 * lda + c0;  pa1 = Ablk + (long)r1 * lda + c1;
    pa2 = Ablk + (long)r2 * lda + c2;  pa3 = Ablk + (long)r3 * lda + c3;
    pb0 = Wblk + (long)r0 * ldw + c0;  pb1 = Wblk + (long)r1 * ldw + c1;
    pb2 = Wblk + (long)r2 * ldw + c2;  pb3 = Wblk + (long)r3 * ldw + c3;
  }

  const unsigned ldsbase = (unsigned)(size_t)(void*)lds;
  const unsigned laneA = (unsigned)((wr * 128 + lm) * 128 + ((hi ^ l7) << 4));
  const unsigned laneB = (unsigned)(32768 + (wc * 64 + lm) * 128 + ((hi ^ l7) << 4));

  f32x4 acc[8][4];
#pragma unroll
  for (int m = 0; m < 8; ++m)
#pragma unroll
    for (int n = 0; n < 4; ++n) acc[m][n] = (f32x4){0.f, 0.f, 0.f, 0.f};

  STAGE_ADV(0);        // K-tile 0 -> buf0
  STAGE_ADV(32768);    // K-tile 1 -> buf1

#pragma unroll 1
  for (int s = 0; s < NS; ++s) {
    // Counted entry wait: <=8 outstanding means this buffer's loads retired
    // (in-order vmcnt); the next tile's 8 stay in flight.
    if (s == NS - 1) asm volatile("s_waitcnt vmcnt(0)" ::: "memory");
    else             asm volatile("s_waitcnt vmcnt(8)" ::: "memory");
    __builtin_amdgcn_s_barrier();

    const unsigned base = ldsbase + (unsigned)((s & 1) * 65536);
    const unsigned a0 = base + laneA, b0 = base + laneB;
    const unsigned a1 = a0 ^ 64u, b1 = b0 ^ 64u;   // k-half toggle (slot bit2)
    short8_t a8[8], b8[4];

    // ---- sub-phase ks=0 ----
    DSR(a8[0], a0, "0");    DSR(a8[1], a0, "2048");  DSR(a8[2], a0, "4096");
    DSR(a8[3], a0, "6144"); DSR(a8[4], a0, "8192");  DSR(a8[5], a0, "10240");
    DSR(a8[6], a0, "12288");DSR(a8[7], a0, "14336");
    DSR(b8[0], b0, "0");    DSR(b8[1], b0, "2048");  DSR(b8[2], b0, "4096");
    DSR(b8[3], b0, "6144");
    asm volatile("s_waitcnt lgkmcnt(0)" ::: "memory");
    __builtin_amdgcn_sched_barrier(0);             // rule #18
    __builtin_amdgcn_s_setprio(1);
#pragma unroll
    for (int mf = 0; mf < 8; ++mf)
#pragma unroll
      for (int nf = 0; nf < 4; ++nf)
        acc[mf][nf] = __builtin_amdgcn_mfma_f32_16x16x32_bf16(a8[mf], b8[nf],
                                                              acc[mf][nf], 0, 0, 0);
    __builtin_amdgcn_s_setprio(0);

    // ---- sub-phase ks=1 ----
    DSR(a8[0], a1, "0");    DSR(a8[1], a1, "2048");  DSR(a8[2], a1, "4096");
    DSR(a8[3], a1, "6144"); DSR(a8[4], a1, "8192");  DSR(a8[5], a1, "10240");
    DSR(a8[6], a1, "12288");DSR(a8[7], a1, "14336");
    DSR(b8[0], b1, "0");    DSR(b8[1], b1, "2048");  DSR(b8[2], b1, "4096");
    DSR(b8[3], b1, "6144");
    asm volatile("s_waitcnt lgkmcnt(0)" ::: "memory");
    __builtin_amdgcn_sched_barrier(0);             // rule #18
    __builtin_amdgcn_s_barrier();                  // all waves' reads retired
    __builtin_amdgcn_sched_barrier(0);             // pin restage below barrier
    if (s + 2 < NS) STAGE_ADV((s & 1) * 32768);    // restage this buffer (t+2)
    __builtin_amdgcn_s_setprio(1);
#pragma unroll
    for (int mf = 0; mf < 8; ++mf)
#pragma unroll
      for (int nf = 0; nf < 4; ++nf)
        acc[mf][nf] = __builtin_amdgcn_mfma_f32_16x16x32_bf16(a8[mf], b8[nf],
                                                              acc[mf][nf], 0, 0, 0);
    __builtin_amdgcn_s_setprio(0);
  }

  // Epilogue: wave writes 128x64 at (mBase + wr*128, nBase + wc*64).
#pragma unroll
  for (int mf = 0; mf < 8; ++mf)
#pragma unroll
    for (int nf = 0; nf < 4; ++nf)
#pragma unroll
      for (int j = 0; j < 4; ++j) {
        const long row = mBase + wr * 128 + mf * 16 + hi * 4 + j;
        const int col = (int)nBase + wc * 64 + nf * 16 + lm;
        const float v = acc[mf][nf][j];
        if (EPI == 0) {
          if (col < HIDc) {
            float rr = sigf(v + bias0[col]);
            float st = __bfloat162float(stbf[row * 2048 + 1024 + col]);
            out0[row * HIDc + col] = __float2bfloat16(rr * st);
          } else {
            int c = col - HIDc;
            out1[row * HIDc + c] = __float2bfloat16(sigf(v + bias1[c]));
          }
        } else if (EPI == 1) {
          if (col < HIDc) {
            out0[row * 2048 + col] = __float2bfloat16(fmaxf(v + bias0[col], 0.f));
          } else {
            int c = col - HIDc;
            out1[row * HIDc + c] = __float2bfloat16(v + bias1[c]);
          }
        } else if (EPI == 2) {
          out0[row * 2048 + HIDc + col] = __float2bfloat16(fmaxf(v + bias0[col], 0.f));
        } else if (EPI == 3) {
          const long idx = row * HIDc + col;
          out0[idx] = __float2bfloat16(tanh_fast(v + __bfloat162float(auxbf[idx])));
        } else {
          const long idx = row * HIDc + col;
          float g = sigf(v + bias0[col]);
          float u = __bfloat162float(U[idx]);
          float cb = __bfloat162float(CB[idx]);
          float st = __bfloat162float(stbf[row * 2048 + 1024 + col]);
          outf[idx] = u * st + (1.f - u) * cb * g;
        }
      }
}

// One prep kernel: blocks [0,10240) transpose all 7 weight views to (N,K)
// bf16; blocks [10240,12288) pack activations to bf16 (A1=[x|state], NB).
__global__ __launch_bounds__(256)
void prep_k(const float4* __restrict__ in4, const float4* __restrict__ st4,
            __hip_bfloat16* __restrict__ A1, __hip_bfloat16* __restrict__ NB,
            const float* __restrict__ Wr, const float* __restrict__ Wu,
            const float* __restrict__ W1, const float* __restrict__ Wc,
            const float* __restrict__ W2, const float* __restrict__ Wg,
            __hip_bfloat16* __restrict__ Wru_t, __hip_bfloat16* __restrict__ W1cx_t,
            __hip_bfloat16* __restrict__ Wcb_t, __hip_bfloat16* __restrict__ W2_t,
            __hip_bfloat16* __restrict__ Wg_t) {
  const int bid = blockIdx.x;
  if (bid < 10240) {
    const float* s_; __hip_bfloat16* d_; long ldo; int j, ktiles;
    if (bid < 2048)      { j = bid;        s_ = Wr; d_ = Wru_t;               ldo = 2048; ktiles = 64; }
    else if (bid < 4096) { j = bid - 2048; s_ = Wu; d_ = Wru_t + 1024L * 2048; ldo = 2048; ktiles = 64; }
    else if (bid < 5120) { j = bid - 4096; s_ = W1; d_ = W1cx_t;              ldo = 1024; ktiles = 32; }
    else if (bid < 6144) { j = bid - 5120; s_ = Wc; d_ = W1cx_t + 1024L * 1024; ldo = 1024; ktiles = 32; }
    else if (bid < 7168) { j = bid - 6144; s_ = Wc + 1024L * 1024; d_ = Wcb_t; ldo = 1024; ktiles = 32; }
    else if (bid < 8192) { j = bid - 7168; s_ = W2; d_ = W2_t;                ldo = 1024; ktiles = 32; }
    else                 { j = bid - 8192; s_ = Wg; d_ = Wg_t;                ldo = 2048; ktiles = 64; }
    const int k0 = (j % ktiles) * 32, n0 = (j / ktiles) * 32;
    __shared__ float t[32][33];
    const int tx = threadIdx.x & 31, ty = threadIdx.x >> 5;
#pragma unroll
    for (int dy = 0; dy < 32; dy += 8)
      t[ty + dy][tx] = s_[(long)(k0 + ty + dy) * 1024 + n0 + tx];
    __syncthreads();
#pragma unroll
    for (int dy = 0; dy < 32; dy += 8)
      d_[(long)(n0 + ty + dy) * ldo + k0 + tx] = __float2bfloat16(t[tx][ty + dy]);
  } else {
    const long NI4 = (long)Bsz * 2048 / 4;
    const long NS4 = (long)Bsz * 1024 / 4;
    for (long i = (long)(bid - 10240) * 256 + threadIdx.x; i < NI4 + NS4;
         i += 2048L * 256) {
      float4 v;
      __hip_bfloat16* dst;
      if (i < NI4) {
        v = in4[i];
        long e = i << 2;
        long row = e >> 11;
        int col = (int)(e & 2047);
        dst = (col < 1024) ? (A1 + row * 2048 + col) : (NB + row * 1024 + (col - 1024));
      } else {
        long jj = i - NI4;
        v = st4[jj];
        long e = jj << 2;
        long row = e >> 10;
        int col = (int)(e & 1023);
        dst = A1 + row * 2048 + 1024 + col;
      }
      union { __hip_bfloat16 h[4]; s16x4 s; } u;
      u.h[0] = __float2bfloat16(v.x);
      u.h[1] = __float2bfloat16(v.y);
      u.h[2] = __float2bfloat16(v.z);
      u.h[3] = __float2bfloat16(v.w);
      *reinterpret_cast<s16x4*>(dst) = u.s;
    }
  }
}

extern "C" void kernel_launch(void* const* d_in, const int* in_sizes, int n_in,
                              void* d_out, int out_size, void* d_ws, size_t ws_size,
                              hipStream_t stream) {
  const float* inputs = (const float*)d_in[0];
  const float* state = (const float*)d_in[1];
  const float* Wr = (const float*)d_in[2];
  const float* br = (const float*)d_in[3];
  const float* Wu = (const float*)d_in[4];
  const float* bu = (const float*)d_in[5];
  const float* Wc = (const float*)d_in[6];
  const float* bc = (const float*)d_in[7];
  const float* W1 = (const float*)d_in[8];
  const float* b1 = (const float*)d_in[9];
  const float* W2 = (const float*)d_in[10];
  const float* b2 = (const float*)d_in[11];
  const float* Wg = (const float*)d_in[12];
  const float* bg = (const float*)d_in[13];
  float* out = (float*)d_out;

  char* ws = (char*)d_ws;
  __hip_bfloat16* A1    = (__hip_bfloat16*)(ws);                 // 64 MB [x|state]
  __hip_bfloat16* NB    = (__hip_bfloat16*)(ws + 67108864L);     // 32 MB neighbors -> CB
  __hip_bfloat16* RS    = (__hip_bfloat16*)(ws + 100663296L);    // 32 MB r*state
  __hip_bfloat16* Ub    = (__hip_bfloat16*)(ws + 134217728L);    // 32 MB u
  __hip_bfloat16* SN    = (__hip_bfloat16*)(ws + 167772160L);    // 64 MB [sem|nei]
  __hip_bfloat16* CXb   = (__hip_bfloat16*)(ws + 234881024L);    // 32 MB x@Wc_top+bc
  __hip_bfloat16* Wru_t = (__hip_bfloat16*)(ws + 268435456L);    // 8 MB  (2048 x 2048)
  __hip_bfloat16* W1cx_t= (__hip_bfloat16*)(ws + 276824064L);    // 4 MB  (2048 x 1024)
  __hip_bfloat16* Wcb_t = (__hip_bfloat16*)(ws + 281018368L);    // 2 MB  (1024 x 1024)
  __hip_bfloat16* W2_t  = (__hip_bfloat16*)(ws + 283115520L);    // 2 MB  (1024 x 1024)
  __hip_bfloat16* Wg_t  = (__hip_bfloat16*)(ws + 285212672L);    // 4 MB  (1024 x 2048)
  __hip_bfloat16* CB    = NB;   // NB dead after G3; reuse for tanh(c)

  prep_k<<<12288, 256, 0, stream>>>((const float4*)inputs, (const float4*)state,
                                    A1, NB, Wr, Wu, W1, Wc, W2, Wg,
                                    Wru_t, W1cx_t, Wcb_t, W2_t, Wg_t);

  // G1: [x|state] @ [Wr|Wu] -> rs, u   (64 m x 8 n)
  gemm256<0><<<512, 512, 0, stream>>>(A1, 2048, Wru_t, 2048, 8,
                                      br, bu, A1, nullptr, nullptr, nullptr,
                                      RS, Ub, nullptr);
  // G2: x @ [W1|Wc_top] -> sem, cx
  gemm256<1><<<512, 512, 0, stream>>>(A1, 2048, W1cx_t, 1024, 8,
                                      b1, bc, nullptr, nullptr, nullptr, nullptr,
                                      SN, CXb, nullptr);
  // G3: neighbors @ W2 -> nei
  gemm256<2><<<256, 512, 0, stream>>>(NB, 1024, W2_t, 1024, 4,
                                      b2, nullptr, nullptr, nullptr, nullptr, nullptr,
                                      SN, nullptr, nullptr);
  // final_c: cb = tanh(cx + rs @ Wc_bot^T) -> CB
  gemm256<3><<<256, 512, 0, stream>>>(RS, 1024, Wcb_t, 1024, 4,
                                      nullptr, nullptr, nullptr, CXb, nullptr, nullptr,
                                      CB, nullptr, nullptr);
  // final_g: out = u*state + (1-u)*cb*sigmoid([sem|nei] @ Wg^T + bg)
  gemm256<4><<<256, 512, 0, stream>>>(SN, 2048, Wg_t, 2048, 4,
                                      bg, nullptr, A1, nullptr, CB, Ub,
                                      nullptr, nullptr, out);
}